// Round 8
// baseline (542.406 us; speedup 1.0000x reference)
//
#include <hip/hip_runtime.h>
#include <stdint.h>
#include <math.h>

#define NN   8192
#define IND  256
#define HID  16
#define KN   6
#define QN   4        // j-range quarters (one per wave in k2)
#define QW   (NN/QN)  // cols per quarter = 2048

typedef short s8v  __attribute__((ext_vector_type(8)));   // 8 bf16 in 4 VGPRs
typedef float f4v  __attribute__((ext_vector_type(4)));

__device__ __forceinline__ uint64_t kmax(uint64_t a, uint64_t b) { return a > b ? a : b; }
__device__ __forceinline__ uint64_t kmin(uint64_t a, uint64_t b) { return a < b ? a : b; }

// RNE float -> bf16 (top 16 bits), returned as bits<<16 float too
__device__ __forceinline__ uint32_t bf16_rne_bits(float x) {
    const uint32_t u = __float_as_uint(x);
    return (u + 0x7FFFu + ((u >> 16) & 1u)) & 0xFFFF0000u;
}

// ---------------------------------------------------------------------------
// k1: h[i] = normalize(x[i] @ W^T + b), also zero rs[i].
// ---------------------------------------------------------------------------
__global__ __launch_bounds__(256) void k1_embed(const float* __restrict__ x,
                                                const float* __restrict__ W,
                                                const float* __restrict__ b,
                                                float* __restrict__ h,
                                                float* __restrict__ rs)
{
    const int lane = threadIdx.x & 63;
    const int wv   = threadIdx.x >> 6;
    const int row  = blockIdx.x * 4 + wv;

    const float4 xv = *(const float4*)(x + (size_t)row * IND + lane * 4);

    float acc[HID];
#pragma unroll
    for (int k = 0; k < HID; ++k) {
        const float4 wv4 = *(const float4*)(W + (size_t)k * IND + lane * 4);
        float v = xv.x * wv4.x + xv.y * wv4.y + xv.z * wv4.z + xv.w * wv4.w;
#pragma unroll
        for (int m = 32; m >= 1; m >>= 1) v += __shfl_xor(v, m, 64);
        acc[k] = v;
    }

    if (lane == 0) {
        float hv[HID];
        float ss = 0.f;
#pragma unroll
        for (int k = 0; k < HID; ++k) { hv[k] = acc[k] + b[k]; ss += hv[k] * hv[k]; }
        const float nrm = fmaxf(sqrtf(ss), 1e-12f);
#pragma unroll
        for (int k = 0; k < HID; ++k) hv[k] = hv[k] / nrm;
        float4* hp = (float4*)(h + (size_t)row * HID);
        hp[0] = make_float4(hv[0],  hv[1],  hv[2],  hv[3]);
        hp[1] = make_float4(hv[4],  hv[5],  hv[6],  hv[7]);
        hp[2] = make_float4(hv[8],  hv[9],  hv[10], hv[11]);
        hp[3] = make_float4(hv[12], hv[13], hv[14], hv[15]);
        rs[row] = 0.f;
    }
}

// ---------------------------------------------------------------------------
// k1b: split h into 3 exact bf16 limbs (hi+mid+lo) and build the 5 K=32
// MFMA operand packings. Slot s<16 holds k=s of limb L1, s>=16 k=s-16 of L2:
//   PA1=[hi |hi ]  PA2=[mid|hi ]  PA3=[lo |mid]   (A-side, i rows)
//   PB1=[hi |mid]  PB2=[hi |lo ]                  (B-side, j cols; MFMA3 reuses PB1)
// 3 MFMAs then cover hihi+himid+midhi+midmid+hilo+lohi: per-sim err ~6e-8.
// ---------------------------------------------------------------------------
__global__ __launch_bounds__(256) void k1b_split(const float* __restrict__ h,
                                                 ushort* __restrict__ PA1,
                                                 ushort* __restrict__ PA2,
                                                 ushort* __restrict__ PA3,
                                                 ushort* __restrict__ PB1,
                                                 ushort* __restrict__ PB2)
{
    const int t   = blockIdx.x * 256 + threadIdx.x;   // < NN*32
    const int row = t >> 5;
    const int s   = t & 31;
    const int k   = s & 15;

    const float x = h[(size_t)row * HID + k];
    const uint32_t hb = bf16_rne_bits(x);
    const float r1 = x - __uint_as_float(hb);
    const uint32_t mb = bf16_rne_bits(r1);
    const float r2 = r1 - __uint_as_float(mb);
    const uint32_t lb = bf16_rne_bits(r2);
    const ushort hi = (ushort)(hb >> 16);
    const ushort mi = (ushort)(mb >> 16);
    const ushort lo = (ushort)(lb >> 16);

    const bool f = (s < 16);
    PA1[t] = hi;
    PA2[t] = f ? mi : hi;
    PA3[t] = f ? lo : mi;
    PB1[t] = f ? hi : mi;
    PB2[t] = f ? hi : lo;
}

// ---------------------------------------------------------------------------
// k2: MFMA sim scan + top-8. Block = 4 waves; wave w of block b owns the
// 16-row strip b and col quarter w (2048 cols = 128 16x16 tiles). Per tile:
// 2 global b128 B-frag loads (L2-resident packs) + 3 chained
// mfma_f32_16x16x32_bf16. C layout: col=lane&15, row=(lane>>4)*4+reg — so
// lane L's 4 C values share col = tile*16+(L&15) (== its B-frag col) and
// cover rows q*4+{0..3}. Per-lane top-8 per row + shared threshold
// (refreshed over the 16-lane row-group every 16 tiles), 4-step butterfly
// merge, per-quarter sorted u64 list out. No LDS, no barriers.
// ---------------------------------------------------------------------------
__global__ __launch_bounds__(256, 4) void k2_topk(const ushort* __restrict__ PA1,
                                                  const ushort* __restrict__ PA2,
                                                  const ushort* __restrict__ PA3,
                                                  const ushort* __restrict__ PB1,
                                                  const ushort* __restrict__ PB2,
                                                  uint64_t* __restrict__ pp)
{
    const int lane = threadIdx.x & 63;
    const int qtr  = threadIdx.x >> 6;        // quarter 0..3
    const int row0 = blockIdx.x * 16;         // strip
    const int col0 = qtr * QW;
    const int m    = lane & 15;
    const int q    = lane >> 4;

    // A-frags: row = row0 + m, k-slots q*8..q*8+7  (persist in regs)
    const size_t aoff = ((size_t)(row0 + m) << 5) + (q << 3);
    const s8v a1 = *(const s8v*)(PA1 + aoff);
    const s8v a2 = *(const s8v*)(PA2 + aoff);
    const s8v a3 = *(const s8v*)(PA3 + aoff);

    float    kv[4][8];
    uint32_t ki[4][8];
    float    thr[4];
#pragma unroll
    for (int g = 0; g < 4; ++g) {
#pragma unroll
        for (int t = 0; t < 8; ++t) { kv[g][t] = -INFINITY; ki[g][t] = 0u; }
        thr[g] = -INFINITY;
    }

    for (int t = 0; t < QW / 16; ++t) {
        const uint32_t col = (uint32_t)(col0 + t * 16 + m);
        const size_t boff = ((size_t)col << 5) + (q << 3);
        const s8v b1 = *(const s8v*)(PB1 + boff);
        const s8v b2 = *(const s8v*)(PB2 + boff);

        f4v acc = {0.f, 0.f, 0.f, 0.f};
        acc = __builtin_amdgcn_mfma_f32_16x16x32_bf16(a1, b1, acc, 0, 0, 0);
        acc = __builtin_amdgcn_mfma_f32_16x16x32_bf16(a2, b2, acc, 0, 0, 0);
        acc = __builtin_amdgcn_mfma_f32_16x16x32_bf16(a3, b1, acc, 0, 0, 0);

#pragma unroll
        for (int g = 0; g < 4; ++g) {
            const float v = acc[g];
            if (__builtin_expect(v > thr[g], 0)) {
                kv[g][7] = v; ki[g][7] = col;
#pragma unroll
                for (int s = 7; s >= 1; --s) {      // bubble up, strict >
                    const bool sw = kv[g][s] > kv[g][s - 1];
                    const float    av = sw ? kv[g][s]     : kv[g][s - 1];
                    const float    bv = sw ? kv[g][s - 1] : kv[g][s];
                    const uint32_t ai = sw ? ki[g][s]     : ki[g][s - 1];
                    const uint32_t bi = sw ? ki[g][s - 1] : ki[g][s];
                    kv[g][s - 1] = av; kv[g][s] = bv;
                    ki[g][s - 1] = ai; ki[g][s] = bi;
                }
                thr[g] = fmaxf(thr[g], kv[g][7]);
            }
        }

        if ((t & 15) == 15) {   // refresh shared threshold over 16-lane row-group
#pragma unroll
            for (int g = 0; g < 4; ++g) {
                float tm = kv[g][7];
#pragma unroll
                for (int mm = 8; mm >= 1; mm >>= 1)
                    tm = fmaxf(tm, __shfl_xor(tm, mm, 64));
                thr[g] = fmaxf(thr[g], tm);
            }
        }
    }

    // per row: pack u64 keys and butterfly-merge across the 16-lane group
#pragma unroll
    for (int g = 0; g < 4; ++g) {
        uint64_t lst[8];
#pragma unroll
        for (int t = 0; t < 8; ++t) {
            uint32_t u = __float_as_uint(kv[g][t]);
            u = (u & 0x80000000u) ? ~u : (u | 0x80000000u);
            lst[t] = ((uint64_t)u << 32) | (uint64_t)(~ki[g][t]);
        }

#pragma unroll
        for (int mm = 1; mm < 16; mm <<= 1) {
            uint64_t o[8];
#pragma unroll
            for (int t = 0; t < 8; ++t)
                o[t] = (uint64_t)__shfl_xor((unsigned long long)lst[t], mm, 64);
            uint64_t X[8];
#pragma unroll
            for (int t = 0; t < 8; ++t) X[t] = kmax(lst[t], o[7 - t]);
#define CSWP(i, jx) { const uint64_t hi = kmax(X[i], X[jx]); const uint64_t lo = kmin(X[i], X[jx]); X[i] = hi; X[jx] = lo; }
            CSWP(0,4) CSWP(1,5) CSWP(2,6) CSWP(3,7)
            CSWP(0,2) CSWP(1,3) CSWP(4,6) CSWP(5,7)
            CSWP(0,1) CSWP(2,3) CSWP(4,5) CSWP(6,7)
#undef CSWP
#pragma unroll
            for (int t = 0; t < 8; ++t) lst[t] = X[t];
        }

        if (m == 0) {
            const int row = row0 + q * 4 + g;
            uint64_t* dst = pp + ((size_t)qtr * NN + row) * 8;
#pragma unroll
            for (int t = 0; t < 8; ++t) dst[t] = lst[t];
        }
    }
}

// ---------------------------------------------------------------------------
// k2m: 4-way merge of the per-quarter sorted lists; emit neighbor idx/val
// (rank 0 = self, dropped). One thread per row. Keys are distinct (idx).
// ---------------------------------------------------------------------------
__global__ __launch_bounds__(256) void k2_merge(const uint64_t* __restrict__ pp,
                                                int* __restrict__ nbr_idx,
                                                float* __restrict__ nbr_val)
{
    const int row = blockIdx.x * 256 + threadIdx.x;
    const uint64_t* L0 = pp + ((size_t)0 * NN + row) * 8;
    const uint64_t* L1 = pp + ((size_t)1 * NN + row) * 8;
    const uint64_t* L2 = pp + ((size_t)2 * NN + row) * 8;
    const uint64_t* L3 = pp + ((size_t)3 * NN + row) * 8;
    int i0 = 0, i1 = 0, i2 = 0, i3 = 0;
#pragma unroll
    for (int t = 0; t < 7; ++t) {
        const uint64_t h0 = L0[i0], h1 = L1[i1], h2 = L2[i2], h3 = L3[i3];
        const uint64_t m01 = kmax(h0, h1), m23 = kmax(h2, h3);
        const uint64_t sel = kmax(m01, m23);
        if      (sel == h0) ++i0;
        else if (sel == h1) ++i1;
        else if (sel == h2) ++i2;
        else                ++i3;
        if (t >= 1) {
            uint32_t u = (uint32_t)(sel >> 32);
            u = (u & 0x80000000u) ? (u & 0x7fffffffu) : ~u;
            nbr_val[(size_t)row * KN + (t - 1)] = __uint_as_float(u);
            nbr_idx[(size_t)row * KN + (t - 1)] = (int)~(uint32_t)sel;
        }
    }
}

// ---------------------------------------------------------------------------
// k3: zero-fill d_out — grid-stride, plain coherent float4 stores
// ---------------------------------------------------------------------------
__global__ __launch_bounds__(256) void k3_zero(float4* __restrict__ out)
{
    const size_t base = (size_t)blockIdx.x * 1024 + threadIdx.x;
    const float4 z = make_float4(0.f, 0.f, 0.f, 0.f);
#pragma unroll
    for (int q = 0; q < 4; ++q)
        out[base + (size_t)q * 256] = z;
}

// ---------------------------------------------------------------------------
// k4: rs[i] = row sums of symmetrized sparse matrix
// ---------------------------------------------------------------------------
__global__ __launch_bounds__(256) void k4_rowsum(const int* __restrict__ nbr_idx,
                                                 const float* __restrict__ nbr_val,
                                                 float* __restrict__ rs)
{
    const int e = blockIdx.x * 256 + threadIdx.x;
    const int i = e / KN;
    const int j = nbr_idx[e];
    const float v = nbr_val[e] * 0.5f;
    atomicAdd(&rs[i], v);
    atomicAdd(&rs[j], v);
}

// ---------------------------------------------------------------------------
// k5: scatter normalized values into pre-zeroed dense output
// ---------------------------------------------------------------------------
__global__ __launch_bounds__(256) void k5_scatter(const int* __restrict__ nbr_idx,
                                                  const float* __restrict__ nbr_val,
                                                  const float* __restrict__ rs,
                                                  float* __restrict__ out)
{
    const int e = blockIdx.x * 256 + threadIdx.x;
    const int i = e / KN;
    const int j = nbr_idx[e];
    const float v = nbr_val[e] * 0.5f;
    const float wi = v / (rs[i] + 1e-8f);
    const float wj = v / (rs[j] + 1e-8f);
    atomicAdd(out + (size_t)i * NN + j, wi);
    atomicAdd(out + (size_t)j * NN + i, wj);
}

// ---------------------------------------------------------------------------
extern "C" void kernel_launch(void* const* d_in, const int* in_sizes, int n_in,
                              void* d_out, int out_size, void* d_ws, size_t ws_size,
                              hipStream_t stream)
{
    const float* x = (const float*)d_in[0];   // 8192 x 256
    const float* W = (const float*)d_in[1];   // 16 x 256
    const float* b = (const float*)d_in[2];   // 16
    float* out = (float*)d_out;               // 8192 x 8192

    // workspace layout (~5.5 MB); pp first for 8B alignment
    uint64_t* pp = (uint64_t*)d_ws;                  // QN*NN*8 keys (2 MB)
    float* h  = (float*)(pp + (size_t)QN * NN * 8);  // NN*HID
    float* rs = h + (size_t)NN * HID;                // NN
    float* nv = rs + NN;                             // NN*KN
    int*   ni = (int*)(nv + (size_t)NN * KN);        // NN*KN
    ushort* PA1 = (ushort*)(ni + (size_t)NN * KN);   // NN*32 each, 16B-aligned
    ushort* PA2 = PA1 + (size_t)NN * 32;
    ushort* PA3 = PA2 + (size_t)NN * 32;
    ushort* PB1 = PA3 + (size_t)NN * 32;
    ushort* PB2 = PB1 + (size_t)NN * 32;

    k1_embed <<<NN / 4,            256, 0, stream>>>(x, W, b, h, rs);
    k1b_split<<<(NN * 32) / 256,   256, 0, stream>>>(h, PA1, PA2, PA3, PB1, PB2);
    k2_topk  <<<NN / 16,           256, 0, stream>>>(PA1, PA2, PA3, PB1, PB2, pp);
    k2_merge <<<NN / 256,          256, 0, stream>>>(pp, ni, nv);
    k3_zero  <<<(int)(((size_t)NN * NN / 4) / 1024), 256, 0, stream>>>((float4*)out);
    k4_rowsum<<<(NN * KN) / 256,   256, 0, stream>>>(ni, nv, rs);
    k5_scatter<<<(NN * KN) / 256,  256, 0, stream>>>(ni, nv, rs, out);
}

// Round 9
// 436.161 us; speedup vs baseline: 1.2436x; 1.2436x over previous
//
#include <hip/hip_runtime.h>
#include <stdint.h>
#include <math.h>

#define NN   8192
#define IND  256
#define HID  16
#define KN   6
#define SN   8        // j-range segments (2 blocks x 4 waves cover a 16-row strip)
#define SW   (NN/SN)  // cols per segment = 1024
#define NT   (SW/16)  // 16-col tiles per segment = 64

typedef short s8v  __attribute__((ext_vector_type(8)));   // 8 bf16 in 4 VGPRs
typedef float f4v  __attribute__((ext_vector_type(4)));

__device__ __forceinline__ uint64_t kmax(uint64_t a, uint64_t b) { return a > b ? a : b; }
__device__ __forceinline__ uint64_t kmin(uint64_t a, uint64_t b) { return a < b ? a : b; }

// order-preserving float<->uint flips
__device__ __forceinline__ uint32_t fflip(float f) {
    const uint32_t u = __float_as_uint(f);
    return (u & 0x80000000u) ? ~u : (u | 0x80000000u);
}
__device__ __forceinline__ float funflip(uint32_t u) {
    return __uint_as_float((u & 0x80000000u) ? (u & 0x7fffffffu) : ~u);
}
#define WM_NEGINF 0x007FFFFFu   // fflip(-INF)

// RNE float -> bf16 bits (top 16)
__device__ __forceinline__ uint32_t bf16_rne_bits(float x) {
    const uint32_t u = __float_as_uint(x);
    return (u + 0x7FFFu + ((u >> 16) & 1u)) & 0xFFFF0000u;
}

// ---------------------------------------------------------------------------
// k1: h[i] = normalize(x[i] @ W^T + b), also zero rs[i].
// ---------------------------------------------------------------------------
__global__ __launch_bounds__(256) void k1_embed(const float* __restrict__ x,
                                                const float* __restrict__ W,
                                                const float* __restrict__ b,
                                                float* __restrict__ h,
                                                float* __restrict__ rs)
{
    const int lane = threadIdx.x & 63;
    const int wv   = threadIdx.x >> 6;
    const int row  = blockIdx.x * 4 + wv;

    const float4 xv = *(const float4*)(x + (size_t)row * IND + lane * 4);

    float acc[HID];
#pragma unroll
    for (int k = 0; k < HID; ++k) {
        const float4 wv4 = *(const float4*)(W + (size_t)k * IND + lane * 4);
        float v = xv.x * wv4.x + xv.y * wv4.y + xv.z * wv4.z + xv.w * wv4.w;
#pragma unroll
        for (int m = 32; m >= 1; m >>= 1) v += __shfl_xor(v, m, 64);
        acc[k] = v;
    }

    if (lane == 0) {
        float hv[HID];
        float ss = 0.f;
#pragma unroll
        for (int k = 0; k < HID; ++k) { hv[k] = acc[k] + b[k]; ss += hv[k] * hv[k]; }
        const float nrm = fmaxf(sqrtf(ss), 1e-12f);
#pragma unroll
        for (int k = 0; k < HID; ++k) hv[k] = hv[k] / nrm;
        float4* hp = (float4*)(h + (size_t)row * HID);
        hp[0] = make_float4(hv[0],  hv[1],  hv[2],  hv[3]);
        hp[1] = make_float4(hv[4],  hv[5],  hv[6],  hv[7]);
        hp[2] = make_float4(hv[8],  hv[9],  hv[10], hv[11]);
        hp[3] = make_float4(hv[12], hv[13], hv[14], hv[15]);
        rs[row] = 0.f;
    }
}

// ---------------------------------------------------------------------------
// k1b: split h into 3 exact bf16 limbs and build the 5 K=32 MFMA packings
// (verified in R8): PA1=[hi|hi] PA2=[mid|hi] PA3=[lo|mid]; PB1=[hi|mid]
// PB2=[hi|lo]. 3 MFMAs cover hihi+himid+midhi+midmid+hilo+lohi (~6e-8 err).
// ---------------------------------------------------------------------------
__global__ __launch_bounds__(256) void k1b_split(const float* __restrict__ h,
                                                 ushort* __restrict__ PA1,
                                                 ushort* __restrict__ PA2,
                                                 ushort* __restrict__ PA3,
                                                 ushort* __restrict__ PB1,
                                                 ushort* __restrict__ PB2)
{
    const int t   = blockIdx.x * 256 + threadIdx.x;   // < NN*32
    const int row = t >> 5;
    const int s   = t & 31;
    const int k   = s & 15;

    const float x = h[(size_t)row * HID + k];
    const uint32_t hb = bf16_rne_bits(x);
    const float r1 = x - __uint_as_float(hb);
    const uint32_t mb = bf16_rne_bits(r1);
    const float r2 = r1 - __uint_as_float(mb);
    const uint32_t lb = bf16_rne_bits(r2);
    const ushort hi = (ushort)(hb >> 16);
    const ushort mi = (ushort)(mb >> 16);
    const ushort lo = (ushort)(lb >> 16);

    const bool f = (s < 16);
    PA1[t] = hi;
    PA2[t] = f ? mi : hi;
    PA3[t] = f ? lo : mi;
    PB1[t] = f ? hi : mi;
    PB2[t] = f ? hi : lo;
}

// ---------------------------------------------------------------------------
// B-frag load: col-major packs, 16B per lane-slot
// ---------------------------------------------------------------------------
__device__ __forceinline__ s8v ldb(const ushort* __restrict__ p, uint32_t col, int q) {
    return *(const s8v*)(p + ((size_t)col << 5) + (q << 3));
}

// one 16x16 tile: 3-limb MFMA chain + exact gated insert
__device__ __forceinline__ void tile_step(const s8v a1, const s8v a2, const s8v a3,
                                          const s8v b1, const s8v b2, uint32_t col,
                                          const float* wmf, uint32_t* wm, int q4,
                                          float kv[4][8], uint32_t ki[4][8])
{
    f4v acc = {0.f, 0.f, 0.f, 0.f};
    acc = __builtin_amdgcn_mfma_f32_16x16x32_bf16(a1, b1, acc, 0, 0, 0);
    acc = __builtin_amdgcn_mfma_f32_16x16x32_bf16(a2, b2, acc, 0, 0, 0);
    acc = __builtin_amdgcn_mfma_f32_16x16x32_bf16(a3, b1, acc, 0, 0, 0);
#pragma unroll
    for (int g = 0; g < 4; ++g) {
        const float v = acc[g];
        // exact prune: v < wm means 8 strictly-greater values exist in this row
        // (cross-segment index ties handled by strict <); v <= own kv7 is a no-op
        if (__builtin_expect(v > kv[g][7] && v >= wmf[g], 0)) {
            kv[g][7] = v; ki[g][7] = col;
#pragma unroll
            for (int s = 7; s >= 1; --s) {      // bubble up, strict >
                const bool sw = kv[g][s] > kv[g][s - 1];
                const float    av = sw ? kv[g][s]     : kv[g][s - 1];
                const float    bv = sw ? kv[g][s - 1] : kv[g][s];
                const uint32_t ai = sw ? ki[g][s]     : ki[g][s - 1];
                const uint32_t bi = sw ? ki[g][s - 1] : ki[g][s];
                kv[g][s - 1] = av; kv[g][s] = bv;
                ki[g][s - 1] = ai; ki[g][s] = bi;
            }
            atomicMax(&wm[q4 + g], fflip(kv[g][7]));   // raise block-row watermark
        }
    }
}

// ---------------------------------------------------------------------------
// k2: MFMA sim scan + top-8. 1024 blocks; block covers 16-row strip
// (blockIdx>>1) ; wave w handles col segment ((blockIdx&1)*4+w), 64 tiles.
// Prefetch ping-pong hides B-frag L2 latency; LDS watermark wm[16]
// (flipped-uint, ds_max_u32, no barrier — monotone so stale reads are safe)
// shared by all 4 waves of the strip gates the insert body.
// C layout (verified R8): col=lane&15, row=(lane>>4)*4+reg.
// ---------------------------------------------------------------------------
__global__ __launch_bounds__(256, 4) void k2_topk(const ushort* __restrict__ PA1,
                                                  const ushort* __restrict__ PA2,
                                                  const ushort* __restrict__ PA3,
                                                  const ushort* __restrict__ PB1,
                                                  const ushort* __restrict__ PB2,
                                                  uint64_t* __restrict__ pp)
{
    __shared__ uint32_t wm[16];

    const int tid  = threadIdx.x;
    const int lane = tid & 63;
    const int wv   = tid >> 6;
    const int seg  = ((blockIdx.x & 1) << 2) | wv;
    const int row0 = (blockIdx.x >> 1) * 16;
    const int col0 = seg * SW;
    const int m    = lane & 15;
    const int q    = lane >> 4;
    const int q4   = q << 2;

    if (tid < 16) wm[tid] = WM_NEGINF;
    __syncthreads();

    // A-frags: row = row0 + m, k-slots q*8..q*8+7 (persist in regs)
    const size_t aoff = ((size_t)(row0 + m) << 5) + (q << 3);
    const s8v a1 = *(const s8v*)(PA1 + aoff);
    const s8v a2 = *(const s8v*)(PA2 + aoff);
    const s8v a3 = *(const s8v*)(PA3 + aoff);

    float    kv[4][8];
    uint32_t ki[4][8];
#pragma unroll
    for (int g = 0; g < 4; ++g)
#pragma unroll
        for (int t = 0; t < 8; ++t) { kv[g][t] = -INFINITY; ki[g][t] = 0u; }

    // prefetch ping-pong over 64 tiles
    uint32_t colc = (uint32_t)(col0 + m);
    s8v c1 = ldb(PB1, colc, q), c2 = ldb(PB2, colc, q);

    for (int t = 0; t < NT; t += 2) {
        // cached watermark (stale <= 2 tiles: monotone, still exact)
        const uint4 wmu = *(const uint4*)&wm[q4];
        float wmf[4];
        wmf[0] = funflip(wmu.x); wmf[1] = funflip(wmu.y);
        wmf[2] = funflip(wmu.z); wmf[3] = funflip(wmu.w);

        const uint32_t coln = (uint32_t)(col0 + (t + 1) * 16 + m);
        s8v n1 = ldb(PB1, coln, q), n2 = ldb(PB2, coln, q);

        tile_step(a1, a2, a3, c1, c2, colc, wmf, wm, q4, kv, ki);

        const int t2 = (t + 2 < NT) ? t + 2 : t;    // clamped redundant tail load
        colc = (uint32_t)(col0 + t2 * 16 + m);
        c1 = ldb(PB1, colc, q); c2 = ldb(PB2, colc, q);

        tile_step(a1, a2, a3, n1, n2, coln, wmf, wm, q4, kv, ki);
    }

    // per row: pack u64 keys and butterfly-merge across the 16-lane group
#pragma unroll
    for (int g = 0; g < 4; ++g) {
        uint64_t lst[8];
#pragma unroll
        for (int t = 0; t < 8; ++t)
            lst[t] = ((uint64_t)fflip(kv[g][t]) << 32) | (uint64_t)(~ki[g][t]);

#pragma unroll
        for (int mm = 1; mm < 16; mm <<= 1) {
            uint64_t o[8];
#pragma unroll
            for (int t = 0; t < 8; ++t)
                o[t] = (uint64_t)__shfl_xor((unsigned long long)lst[t], mm, 64);
            uint64_t X[8];
#pragma unroll
            for (int t = 0; t < 8; ++t) X[t] = kmax(lst[t], o[7 - t]);
#define CSWP(i, jx) { const uint64_t hi = kmax(X[i], X[jx]); const uint64_t lo = kmin(X[i], X[jx]); X[i] = hi; X[jx] = lo; }
            CSWP(0,4) CSWP(1,5) CSWP(2,6) CSWP(3,7)
            CSWP(0,2) CSWP(1,3) CSWP(4,6) CSWP(5,7)
            CSWP(0,1) CSWP(2,3) CSWP(4,5) CSWP(6,7)
#undef CSWP
#pragma unroll
            for (int t = 0; t < 8; ++t) lst[t] = X[t];
        }

        if (m == 0) {
            const int row = row0 + q4 + g;
            uint64_t* dst = pp + ((size_t)seg * NN + row) * 8;
#pragma unroll
            for (int t = 0; t < 8; ++t) dst[t] = lst[t];
        }
    }
}

// ---------------------------------------------------------------------------
// k2m: 8-way merge of per-segment sorted lists; emit neighbor idx/val
// (rank 0 = self, dropped). One thread per row; heads cached in registers.
// ---------------------------------------------------------------------------
__global__ __launch_bounds__(256) void k2_merge(const uint64_t* __restrict__ pp,
                                                int* __restrict__ nbr_idx,
                                                float* __restrict__ nbr_val)
{
    const int row = blockIdx.x * 256 + threadIdx.x;
    uint64_t hd[SN]; int ix[SN];
#pragma unroll
    for (int s = 0; s < SN; ++s) { hd[s] = pp[((size_t)s * NN + row) * 8]; ix[s] = 0; }
#pragma unroll
    for (int t = 0; t < 7; ++t) {
        uint64_t best = hd[0]; int bs = 0;
#pragma unroll
        for (int s = 1; s < SN; ++s)
            if (hd[s] > best) { best = hd[s]; bs = s; }
        ++ix[bs];
        hd[bs] = pp[((size_t)bs * NN + row) * 8 + ix[bs]];   // ix <= 7, in-bounds
        if (t >= 1) {
            uint32_t u = (uint32_t)(best >> 32);
            u = (u & 0x80000000u) ? (u & 0x7fffffffu) : ~u;
            nbr_val[(size_t)row * KN + (t - 1)] = __uint_as_float(u);
            nbr_idx[(size_t)row * KN + (t - 1)] = (int)~(uint32_t)best;
        }
    }
}

// ---------------------------------------------------------------------------
// k3: zero-fill d_out — grid-stride, plain coherent float4 stores
// ---------------------------------------------------------------------------
__global__ __launch_bounds__(256) void k3_zero(float4* __restrict__ out)
{
    const size_t base = (size_t)blockIdx.x * 1024 + threadIdx.x;
    const float4 z = make_float4(0.f, 0.f, 0.f, 0.f);
#pragma unroll
    for (int qq = 0; qq < 4; ++qq)
        out[base + (size_t)qq * 256] = z;
}

// ---------------------------------------------------------------------------
// k4: rs[i] = row sums of symmetrized sparse matrix
// ---------------------------------------------------------------------------
__global__ __launch_bounds__(256) void k4_rowsum(const int* __restrict__ nbr_idx,
                                                 const float* __restrict__ nbr_val,
                                                 float* __restrict__ rs)
{
    const int e = blockIdx.x * 256 + threadIdx.x;
    const int i = e / KN;
    const int j = nbr_idx[e];
    const float v = nbr_val[e] * 0.5f;
    atomicAdd(&rs[i], v);
    atomicAdd(&rs[j], v);
}

// ---------------------------------------------------------------------------
// k5: scatter normalized values into pre-zeroed dense output
// ---------------------------------------------------------------------------
__global__ __launch_bounds__(256) void k5_scatter(const int* __restrict__ nbr_idx,
                                                  const float* __restrict__ nbr_val,
                                                  const float* __restrict__ rs,
                                                  float* __restrict__ out)
{
    const int e = blockIdx.x * 256 + threadIdx.x;
    const int i = e / KN;
    const int j = nbr_idx[e];
    const float v = nbr_val[e] * 0.5f;
    const float wi = v / (rs[i] + 1e-8f);
    const float wj = v / (rs[j] + 1e-8f);
    atomicAdd(out + (size_t)i * NN + j, wi);
    atomicAdd(out + (size_t)j * NN + i, wj);
}

// ---------------------------------------------------------------------------
extern "C" void kernel_launch(void* const* d_in, const int* in_sizes, int n_in,
                              void* d_out, int out_size, void* d_ws, size_t ws_size,
                              hipStream_t stream)
{
    const float* x = (const float*)d_in[0];   // 8192 x 256
    const float* W = (const float*)d_in[1];   // 16 x 256
    const float* b = (const float*)d_in[2];   // 16
    float* out = (float*)d_out;               // 8192 x 8192

    // workspace layout (~8 MB); pp first for 8B alignment
    uint64_t* pp = (uint64_t*)d_ws;                  // SN*NN*8 keys (4 MB)
    float* h  = (float*)(pp + (size_t)SN * NN * 8);  // NN*HID
    float* rs = h + (size_t)NN * HID;                // NN
    float* nv = rs + NN;                             // NN*KN
    int*   ni = (int*)(nv + (size_t)NN * KN);        // NN*KN
    ushort* PA1 = (ushort*)(ni + (size_t)NN * KN);   // NN*32 each, 16B-aligned
    ushort* PA2 = PA1 + (size_t)NN * 32;
    ushort* PA3 = PA2 + (size_t)NN * 32;
    ushort* PB1 = PA3 + (size_t)NN * 32;
    ushort* PB2 = PB1 + (size_t)NN * 32;

    k1_embed <<<NN / 4,            256, 0, stream>>>(x, W, b, h, rs);
    k1b_split<<<(NN * 32) / 256,   256, 0, stream>>>(h, PA1, PA2, PA3, PB1, PB2);
    k2_topk  <<<(NN / 16) * 2,     256, 0, stream>>>(PA1, PA2, PA3, PB1, PB2, pp);
    k2_merge <<<NN / 256,          256, 0, stream>>>(pp, ni, nv);
    k3_zero  <<<(int)(((size_t)NN * NN / 4) / 1024), 256, 0, stream>>>((float4*)out);
    k4_rowsum<<<(NN * KN) / 256,   256, 0, stream>>>(ni, nv, rs);
    k5_scatter<<<(NN * KN) / 256,  256, 0, stream>>>(ni, nv, rs, out);
}